// Round 6
// baseline (134.022 us; speedup 1.0000x reference)
//
#include <hip/hip_runtime.h>

#define NN 1024
#define DFEAT 6
#define TSTEPS 60
#define HID 64
#define RREL 60
#define SENT -1.0e30f

// Fused kernel: blocks [0,1024) = GRU (dispatched first, hides under stream).
// Blocks [1024,3072) = rel stream, 2 pairs per thread, ALL 30 float4 loads
// staged into register arrays before consumption -> ~30 outstanding loads
// per thread (vs ~8 at R3's VGPR=56) to test the MSHR/MLP hypothesis.
__global__ __launch_bounds__(256) void fused_kernel(
    const float* __restrict__ x,      // (1024, 360)
    const float* __restrict__ W_ih,   // (192, 6)
    const float* __restrict__ W_hh,   // (192, 64)
    const float* __restrict__ b_ih,   // (192)
    const float* __restrict__ b_hh,   // (192)
    const float* __restrict__ w_att,  // (188)
    const float* __restrict__ rel,    // (1024, 1024, 60)
    float* __restrict__ h_last,       // (1024, 64)
    float* __restrict__ s_i,          // (1024)
    float* __restrict__ s_j,          // (1024)
    float* __restrict__ temp)         // (1024, 1024): srel or SENT
{
    if (blockIdx.x >= NN) {
        // ---------------- rel stream part ----------------
        const int b  = blockIdx.x - NN;          // 0..2047
        const int i  = b >> 1;
        const int j0 = ((b & 1) << 9) + threadIdx.x;   // j and j+256
        const int j1 = j0 + 256;

        const float4* p0 = reinterpret_cast<const float4*>(rel + ((size_t)i * NN + j0) * RREL);
        const float4* p1 = reinterpret_cast<const float4*>(rel + ((size_t)i * NN + j1) * RREL);

        // stage ALL loads first (independent, no consumption in between)
        float4 v0[15], v1[15];
#pragma unroll
        for (int k = 0; k < 15; ++k) v0[k] = p0[k];
#pragma unroll
        for (int k = 0; k < 15; ++k) v1[k] = p1[k];

        float wrel[RREL];
#pragma unroll
        for (int r = 0; r < RREL; ++r) wrel[r] = w_att[2 * HID + r];

        float s0 = 0.0f, m0 = 0.0f, s1 = 0.0f, m1 = 0.0f;
#pragma unroll
        for (int k = 0; k < 15; ++k) {
            s0 += v0[k].x * wrel[4*k+0] + v0[k].y * wrel[4*k+1]
                + v0[k].z * wrel[4*k+2] + v0[k].w * wrel[4*k+3];
            m0 += v0[k].x + v0[k].y + v0[k].z + v0[k].w;
            s1 += v1[k].x * wrel[4*k+0] + v1[k].y * wrel[4*k+1]
                + v1[k].z * wrel[4*k+2] + v1[k].w * wrel[4*k+3];
            m1 += v1[k].x + v1[k].y + v1[k].z + v1[k].w;
        }
        temp[(size_t)i * NN + j0] = (m0 != 0.0f) ? s0 : SENT;
        temp[(size_t)i * NN + j1] = (m1 != 0.0f) ? s1 : SENT;
        return;
    }

    // ---------------- GRU part (identical to R3) ----------------
    const int n = blockIdx.x;
    const int g = threadIdx.x;

    __shared__ __align__(16) float x_sh[DFEAT * TSTEPS];
    __shared__ __align__(16) float h_sh[HID];
    __shared__ float gi_sh[192];
    __shared__ float gh_sh[192];

    for (int idx = g; idx < DFEAT * TSTEPS; idx += 256)
        x_sh[idx] = x[(size_t)n * (DFEAT * TSTEPS) + idx];

    float whh[HID];
    float wih[DFEAT];
    float bih = 0.0f, bhh = 0.0f;
    if (g < 192) {
#pragma unroll
        for (int k4 = 0; k4 < HID / 4; ++k4) {
            float4 w = *reinterpret_cast<const float4*>(&W_hh[g * HID + k4 * 4]);
            whh[k4 * 4 + 0] = w.x; whh[k4 * 4 + 1] = w.y;
            whh[k4 * 4 + 2] = w.z; whh[k4 * 4 + 3] = w.w;
        }
#pragma unroll
        for (int d = 0; d < DFEAT; ++d) wih[d] = W_ih[g * DFEAT + d];
        bih = b_ih[g];
        bhh = b_hh[g];
    }

    if (g < HID) h_sh[g] = 0.0f;
    __syncthreads();

    for (int t = 0; t < TSTEPS; ++t) {
        if (g < 192) {
            float gi = bih;
#pragma unroll
            for (int d = 0; d < DFEAT; ++d) gi += x_sh[d * TSTEPS + t] * wih[d];

            float gh = bhh;
#pragma unroll
            for (int k4 = 0; k4 < HID / 4; ++k4) {
                float4 hv = *reinterpret_cast<const float4*>(&h_sh[k4 * 4]);
                gh += hv.x * whh[k4 * 4 + 0] + hv.y * whh[k4 * 4 + 1]
                    + hv.z * whh[k4 * 4 + 2] + hv.w * whh[k4 * 4 + 3];
            }
            gi_sh[g] = gi;
            gh_sh[g] = gh;
        }
        __syncthreads();

        if (g < HID) {
            float ir = gi_sh[g],        hr = gh_sh[g];
            float iz = gi_sh[HID + g],  hz = gh_sh[HID + g];
            float in_ = gi_sh[2*HID + g], hn = gh_sh[2*HID + g];
            float r = 1.0f / (1.0f + __expf(-(ir + hr)));
            float z = 1.0f / (1.0f + __expf(-(iz + hz)));
            float nn_ = tanhf(in_ + r * hn);
            float hold = h_sh[g];
            h_sh[g] = (1.0f - z) * nn_ + z * hold;
        }
        __syncthreads();
    }

    if (g < HID) {
        float hv = h_sh[g];
        h_last[(size_t)n * HID + g] = hv;
        float pi = hv * w_att[g];
        float pj = hv * w_att[HID + g];
#pragma unroll
        for (int off = 32; off > 0; off >>= 1) {
            pi += __shfl_down(pi, off);
            pj += __shfl_down(pj, off);
        }
        if (g == 0) { s_i[n] = pi; s_j[n] = pj; }
    }
}

// --------- Kernel 2: weight assembly + softmax + agg matvec + FC -------------
__global__ __launch_bounds__(256) void row_kernel(
    const float* __restrict__ temp,   // (1024, 1024): srel or SENT
    const float* __restrict__ s_i,    // (1024)
    const float* __restrict__ s_j,    // (1024)
    const float* __restrict__ b_att,  // (1)
    const float* __restrict__ h_last, // (1024, 64)
    const float* __restrict__ W_fc,   // (128)
    const float* __restrict__ b_fc,   // (1)
    float* __restrict__ out)          // (1024)
{
    const int i = blockIdx.x;
    const int tid = threadIdx.x;

    __shared__ __align__(16) float pm_sh[NN];
    __shared__ float red_sh[256];

    const float si_b = s_i[i] + b_att[0];
    float4 sv = reinterpret_cast<const float4*>(temp + (size_t)i * NN)[tid];
    float4 sj = reinterpret_cast<const float4*>(s_j)[tid];

    float tvv[4];
    {
        float srels[4] = {sv.x, sv.y, sv.z, sv.w};
        float sjs[4]   = {sj.x, sj.y, sj.z, sj.w};
#pragma unroll
        for (int c = 0; c < 4; ++c) {
            float w = si_b + sjs[c] + srels[c];
            w = (w >= 0.0f) ? w : 0.01f * w;
            float tv = (srels[c] != SENT) ? w : 0.0f;   // mask * weight
            tvv[c] = (tv == 0.0f) ? -10000.0f : tv;
        }
    }
    float m = fmaxf(fmaxf(tvv[0], tvv[1]), fmaxf(tvv[2], tvv[3]));
    red_sh[tid] = m;
    __syncthreads();
    for (int s = 128; s > 0; s >>= 1) {
        if (tid < s) red_sh[tid] = fmaxf(red_sh[tid], red_sh[tid + s]);
        __syncthreads();
    }
    const float M = red_sh[0];
    __syncthreads();

    float lsum = 0.0f;
    float4 pmv;
    {
        float e0 = __expf(tvv[0] - M), e1 = __expf(tvv[1] - M);
        float e2 = __expf(tvv[2] - M), e3 = __expf(tvv[3] - M);
        lsum = e0 + e1 + e2 + e3;                  // denom over ALL j
        pmv.x = (tvv[0] != -10000.0f) ? e0 : 0.0f;
        pmv.y = (tvv[1] != -10000.0f) ? e1 : 0.0f;
        pmv.z = (tvv[2] != -10000.0f) ? e2 : 0.0f;
        pmv.w = (tvv[3] != -10000.0f) ? e3 : 0.0f;
    }
    reinterpret_cast<float4*>(pm_sh)[tid] = pmv;

    red_sh[tid] = lsum;
    __syncthreads();
    for (int s = 128; s > 0; s >>= 1) {
        if (tid < s) red_sh[tid] += red_sh[tid + s];
        __syncthreads();
    }
    const float invS = 1.0f / red_sh[0];
    __syncthreads();

    // agg[h] = invS * sum_j pm[j] * h_last[j][h]
    const int h = tid & (HID - 1);
    const int grp = tid >> 6;                      // 4 groups x 256 j each
    float part = 0.0f;
    const float* hl = h_last + (size_t)grp * 256 * HID + h;
    const float* pm = pm_sh + grp * 256;
#pragma unroll 4
    for (int jc = 0; jc < 256; ++jc)
        part += pm[jc] * hl[(size_t)jc * HID];

    red_sh[tid] = part;
    __syncthreads();

    if (tid < HID) {
        float agg = (red_sh[tid] + red_sh[HID + tid]
                   + red_sh[2 * HID + tid] + red_sh[3 * HID + tid]) * invS;
        float o = h_last[(size_t)i * HID + tid] * W_fc[tid] + agg * W_fc[HID + tid];
#pragma unroll
        for (int off = 32; off > 0; off >>= 1) o += __shfl_down(o, off);
        if (tid == 0) out[i] = o + b_fc[0];
    }
}

extern "C" void kernel_launch(void* const* d_in, const int* in_sizes, int n_in,
                              void* d_out, int out_size, void* d_ws, size_t ws_size,
                              hipStream_t stream) {
    const float* x     = (const float*)d_in[0];
    const float* rel   = (const float*)d_in[1];
    const float* W_ih  = (const float*)d_in[2];
    const float* W_hh  = (const float*)d_in[3];
    const float* b_ih  = (const float*)d_in[4];
    const float* b_hh  = (const float*)d_in[5];
    const float* w_att = (const float*)d_in[6];
    const float* b_att = (const float*)d_in[7];
    const float* W_fc  = (const float*)d_in[8];
    const float* b_fc  = (const float*)d_in[9];

    float* ws     = (float*)d_ws;
    float* h_last = ws;                      // 1024*64
    float* s_i    = ws + NN * HID;           // 1024
    float* s_j    = ws + NN * HID + NN;      // 1024
    float* temp   = ws + NN * HID + 2 * NN;  // 1024*1024

    fused_kernel<<<NN + NN * 2, 256, 0, stream>>>(
        x, W_ih, W_hh, b_ih, b_hh, w_att, rel, h_last, s_i, s_j, temp);
    row_kernel<<<NN, 256, 0, stream>>>(temp, s_i, s_j, b_att, h_last,
                                       W_fc, b_fc, (float*)d_out);
}